// Round 6
// baseline (40.482 us; speedup 1.0000x reference)
//
#include <hip/hip_runtime.h>
#include <math.h>

#define GAMMA 0.3f      // NUM_BASIS / MAX_RADIUS = 3/10
#define WSTR  808       // k2 LDS row stride in bf16 elems (800 + 8 pad; 16B-aligned rows, spread banks)

typedef __bf16 bf16x8 __attribute__((ext_vector_type(8)));
typedef __bf16 bf16x4 __attribute__((ext_vector_type(4)));
typedef float  f32x4  __attribute__((ext_vector_type(4)));

// ---------------------------------------------------------------------------
// K1: W[z,b,h,i] = sum_j x[z,b,j] * rw2[h, i*32+j]  via MFMA, computed ONCE.
// Output layout (bf16): Wg[(((z*16+bc)*50 + hp)*32 + i)*32 + kl]
//   where h = hp*2 + hpar, b_local bl = 0..15, kl = (bl>>2)*8 + hpar*4 + (bl&3)
// kl is chosen so a contiguous 16B LDS read in k2 IS the MFMA B-fragment.
// grid 1600 = (z*16+bc)(64) x nq(25); 4 waves; wave w does n-tiles nq*8+w*2+{0,1}
// ---------------------------------------------------------------------------
__global__ __launch_bounds__(256) void k1_W(const float* __restrict__ x,
                                            const float* __restrict__ rw2,
                                            __bf16* __restrict__ Wg) {
    int bid = blockIdx.x;
    int mt = bid / 25, nq = bid % 25;
    int z = mt >> 4, bc = mt & 15;
    int t = threadIdx.x, w = t >> 6, l = t & 63;
    int l16 = l & 15, lg = l >> 4;

    // A-frag: A[m=l16][k=lg*4+e (+16)] = x[z, bc*16+m, j=k]
    int row = (z * 256 + bc * 16 + l16) * 32;
    float4 v0 = *(const float4*)(x + row + lg * 4);
    float4 v1 = *(const float4*)(x + row + lg * 4 + 16);
    bf16x8 xa;
    xa[0] = (__bf16)v0.x; xa[1] = (__bf16)v0.y; xa[2] = (__bf16)v0.z; xa[3] = (__bf16)v0.w;
    xa[4] = (__bf16)v1.x; xa[5] = (__bf16)v1.y; xa[6] = (__bf16)v1.z; xa[7] = (__bf16)v1.w;

    #pragma unroll
    for (int q = 0; q < 2; ++q) {
        int nt = nq * 8 + w * 2 + q;          // 0..199
        int h = nt >> 1, hpar = h & 1, hp = h >> 1;
        int icol = ((nt & 1) << 4) + l16;     // i = 0..31
        const float* rp = rw2 + h * 1024 + icol * 32 + lg * 4;
        float4 r0 = *(const float4*)rp;
        float4 r1 = *(const float4*)(rp + 16);
        bf16x8 rb;
        rb[0] = (__bf16)r0.x; rb[1] = (__bf16)r0.y; rb[2] = (__bf16)r0.z; rb[3] = (__bf16)r0.w;
        rb[4] = (__bf16)r1.x; rb[5] = (__bf16)r1.y; rb[6] = (__bf16)r1.z; rb[7] = (__bf16)r1.w;
        f32x4 d = {0.f, 0.f, 0.f, 0.f};
        d = __builtin_amdgcn_mfma_f32_16x16x32_bf16(xa, rb, d, 0, 0, 0);
        // D: row(bl) = lg*4+r, col(i) = icol.  kl = lg*8 + hpar*4 + r  -> 4 contiguous
        bf16x4 pk;
        pk[0] = (__bf16)d[0]; pk[1] = (__bf16)d[1]; pk[2] = (__bf16)d[2]; pk[3] = (__bf16)d[3];
        size_t off = ((size_t)((z * 16 + bc) * 50 + hp) * 32 + icol) * 32 + lg * 8 + hpar * 4;
        *(bf16x4*)(Wg + off) = pk;
    }
}

// ---------------------------------------------------------------------------
// K2: part[z,qc,a,i] = sum_{k=(h in hh-half, b in bc)} hid(z,a,b,h) * W[k,i]
// grid 512 = z(4) x bc(16) x hh(2) x ac(4); 256 threads = 4 waves.
// LDS 52.9 KB -> 2 blocks/CU (grid-limited). 25 MFMA k-steps, 2 acc tiles.
// B-frag = single ds_read_b128 per i-tile (Wg layout is register-ordered).
// ---------------------------------------------------------------------------
__global__ __launch_bounds__(256) void k2_fused(const __bf16* __restrict__ Wg,
                                                const float* __restrict__ xyz,
                                                const float* __restrict__ rw1,
                                                float* __restrict__ part) {
    __shared__ __bf16 Wlds[32 * WSTR];   // [i][kl_local], rows 1616 B
    __shared__ float rw1s[304];

    int bid = blockIdx.x;
    int ac = bid & 3;
    int hh = (bid >> 2) & 1;
    int bc = (bid >> 3) & 15;
    int z  = bid >> 7;
    int t  = threadIdx.x, w = t >> 6, l = t & 63;
    int l16 = l & 15, lg = l >> 4;

    for (int e = t; e < 300; e += 256) rw1s[e] = rw1[e];

    // ---- stage W slice: 25 hp x 32 i x 32 kl bf16 = 51,200 elems (coalesced) ----
    const __bf16* gsrc = Wg + ((size_t)((z * 16 + bc) * 50 + hh * 25)) * 1024;
    for (int c = t; c < 3200; c += 256) {              // 16B chunks
        int hp = c >> 7, rem = c & 127;
        int i = rem >> 2, kq = rem & 3;
        uint4 v = *(const uint4*)(gsrc + c * 8);
        *(uint4*)&Wlds[i * WSTR + hp * 32 + kq * 8] = v;
    }

    // ---- per-lane bas registers: a-row = l16, b-set = lg*4+e ----
    int a_glob = ac * 64 + w * 16 + l16;
    float ax = xyz[(z * 256 + a_glob) * 3 + 0];
    float ay = xyz[(z * 256 + a_glob) * 3 + 1];
    float az = xyz[(z * 256 + a_glob) * 3 + 2];
    float bas[4][3];
    #pragma unroll
    for (int e = 0; e < 4; ++e) {
        int b_glob = bc * 16 + lg * 4 + e;
        float dx = xyz[(z * 256 + b_glob) * 3 + 0] - ax;
        float dy = xyz[(z * 256 + b_glob) * 3 + 1] - ay;
        float dz = xyz[(z * 256 + b_glob) * 3 + 2] - az;
        float r  = sqrtf(dx * dx + dy * dy + dz * dz + 1e-12f);
        float r5 = r - 5.f, r10 = r - 10.f;
        bas[e][0] = __expf(-GAMMA * r * r);
        bas[e][1] = __expf(-GAMMA * r5 * r5);
        bas[e][2] = __expf(-GAMMA * r10 * r10);
    }
    __syncthreads();

    // ---- main K loop: 25 steps x (2h x 16b = 32 k) ----
    f32x4 acc0 = {0.f, 0.f, 0.f, 0.f};
    f32x4 acc1 = {0.f, 0.f, 0.f, 0.f};
    for (int ks = 0; ks < 25; ++ks) {
        int h0 = hh * 50 + 2 * ks, h1 = h0 + 1;
        float u00 = rw1s[h0],       u01 = rw1s[h1];
        float u10 = rw1s[100 + h0], u11 = rw1s[100 + h1];
        float u20 = rw1s[200 + h0], u21 = rw1s[200 + h1];
        bf16x8 af;
        #pragma unroll
        for (int e = 0; e < 4; ++e) {
            float p0 = bas[e][0] * u00 + bas[e][1] * u10 + bas[e][2] * u20;
            float p1 = bas[e][0] * u01 + bas[e][1] * u11 + bas[e][2] * u21;
            float s0 = p0 * __builtin_amdgcn_rcpf(1.f + __expf(-p0));   // swish
            float s1 = p1 * __builtin_amdgcn_rcpf(1.f + __expf(-p1));
            af[e]     = (__bf16)s0;    // k = lg*4+e        (h0)
            af[e + 4] = (__bf16)s1;    // k = lg*4+e+16     (h1)
        }
        const __bf16* w0 = &Wlds[l16 * WSTR + ks * 32 + lg * 8];
        bf16x8 bf0 = *(const bf16x8*)w0;                // i-tile 0: frag in order
        bf16x8 bf1 = *(const bf16x8*)(w0 + 16 * WSTR);  // i-tile 1
        acc0 = __builtin_amdgcn_mfma_f32_16x16x32_bf16(af, bf0, acc0, 0, 0, 0);
        acc1 = __builtin_amdgcn_mfma_f32_16x16x32_bf16(af, bf1, acc1, 0, 0, 0);
    }

    // ---- write partials: part[((z*32+qc)*256 + a)*32 + i] ----
    int qc = bc * 2 + hh;
    #pragma unroll
    for (int r = 0; r < 4; ++r) {
        int a = ac * 64 + w * 16 + lg * 4 + r;
        size_t base = ((size_t)(z * 32 + qc) * 256 + a) * 32;
        part[base + l16]      = acc0[r];
        part[base + 16 + l16] = acc1[r];
    }
}

// ---------------------------------------------------------------------------
// K3a: sum over 32 chunks, abs+mask+scale, pool 4 a's per block.
// grid: 256 blocks = z(4) x ag(64); 256 threads = a_loc(4) x qg(2) x i(32)
// ---------------------------------------------------------------------------
__global__ __launch_bounds__(256) void k3a_reduce(const float* __restrict__ part,
                                                  const int* __restrict__ mask,
                                                  float* __restrict__ pooled_part) {
    int blk = blockIdx.x;
    int z = blk >> 6, ag = blk & 63;
    int t = threadIdx.x;
    int i = t & 31;
    int qg = (t >> 5) & 1;
    int a_loc = t >> 6;               // 0..3
    int a = ag * 4 + a_loc;
    const float* base = part + ((size_t)z * 32 * 256 + (size_t)a) * 32 + i;
    float s = 0.f;
    for (int q = qg; q < 32; q += 2)
        s += base[(size_t)q * 8192];
    __shared__ float buf[4][2][32];
    buf[a_loc][qg][i] = s;
    __syncthreads();
    if (t < 128) {
        int al = t >> 5, ii = t & 31;
        float v = buf[al][0][ii] + buf[al][1][ii];
        float sc = (mask[z * 256 + ag * 4 + al] != 0) ? 0.0625f : 0.f;   // 1/sqrt(256)
        buf[al][0][ii] = fabsf(v) * sc;
    }
    __syncthreads();
    if (t < 32) {
        float v = buf[0][0][t] + buf[1][0][t] + buf[2][0][t] + buf[3][0][t];
        pooled_part[(z * 64 + ag) * 32 + t] = v;
    }
}

// ---------------------------------------------------------------------------
// K3b: pool over ag(64), normalize (ddof=1), fc3+leaky, fc2 -> out[4]
// ---------------------------------------------------------------------------
__global__ __launch_bounds__(128) void k3b_final(const float* __restrict__ pooled_part,
                                                 const float* __restrict__ fc3_w,
                                                 const float* __restrict__ fc3_b,
                                                 const float* __restrict__ fc2_w,
                                                 const float* __restrict__ fc2_b,
                                                 float* __restrict__ out) {
    int t = threadIdx.x;
    int z = t >> 5, i = t & 31;
    float s = 0.f;
    for (int ag = 0; ag < 64; ++ag) s += pooled_part[(z * 64 + ag) * 32 + i];
    float sm = s;
    #pragma unroll
    for (int off = 16; off; off >>= 1) sm += __shfl_xor(sm, off, 32);
    float mean = sm * (1.f / 32.f);
    float d = s - mean;
    float ss = d * d;
    #pragma unroll
    for (int off = 16; off; off >>= 1) ss += __shfl_xor(ss, off, 32);
    float stdv = sqrtf(ss * (1.f / 31.f));   // ddof=1
    float nv = d / (stdv + 1e-6f);
    __shared__ float pn[4][32];
    pn[z][i] = nv;
    __syncthreads();
    float h1 = fc3_b[i];
    #pragma unroll
    for (int j = 0; j < 32; ++j) h1 += pn[z][j] * fc3_w[j * 32 + i];
    h1 = (h1 >= 0.f) ? h1 : 0.01f * h1;
    float y = h1 * fc2_w[i];
    #pragma unroll
    for (int off = 16; off; off >>= 1) y += __shfl_xor(y, off, 32);
    if (i == 0) out[z] = y + fc2_b[0];
}

extern "C" void kernel_launch(void* const* d_in, const int* in_sizes, int n_in,
                              void* d_out, int out_size, void* d_ws, size_t ws_size,
                              hipStream_t stream) {
    const float* x    = (const float*)d_in[0];
    const float* xyz  = (const float*)d_in[1];
    const int*   mask = (const int*)d_in[2];
    const float* rw1  = (const float*)d_in[3];
    const float* rw2  = (const float*)d_in[4];
    const float* fc3w = (const float*)d_in[5];
    const float* fc3b = (const float*)d_in[6];
    const float* fc2w = (const float*)d_in[7];
    const float* fc2b = (const float*)d_in[8];
    float* out = (float*)d_out;

    // Wg: 4z*16bc*50hp*32i*32kl bf16 = 6,553,600 B
    // part: 4z*32qc*256a*32i f32     = 4,194,304 B
    __bf16* Wg         = (__bf16*)d_ws;
    float*  part       = (float*)((char*)d_ws + 6553600);
    float*  pooled_part= (float*)((char*)d_ws + 6553600 + 4194304);

    hipLaunchKernelGGL(k1_W,       dim3(1600), dim3(256), 0, stream, x, rw2, Wg);
    hipLaunchKernelGGL(k2_fused,   dim3(512),  dim3(256), 0, stream, Wg, xyz, rw1, part);
    hipLaunchKernelGGL(k3a_reduce, dim3(256),  dim3(256), 0, stream, part, mask, pooled_part);
    hipLaunchKernelGGL(k3b_final,  dim3(1),    dim3(128), 0, stream, pooled_part, fc3w, fc3b, fc2w, fc2b, out);
}

// Round 7
// 34.923 us; speedup vs baseline: 1.1592x; 1.1592x over previous
//
#include <hip/hip_runtime.h>
#include <math.h>

#define GAMMA 0.3f      // NUM_BASIS / MAX_RADIUS = 3/10
#define WSTR  1608      // Wlds row stride in bf16 elems (1600 + 8 pad; 802->402 mod-32 bank spread)

typedef __bf16 bf16x8 __attribute__((ext_vector_type(8)));
typedef __bf16 bf16x4 __attribute__((ext_vector_type(4)));
typedef float  f32x4  __attribute__((ext_vector_type(4)));

// ---------------------------------------------------------------------------
// K2 fused (round-5 structure, 8 waves + split-K):
//  grid 256 = z(4) x bc(16) x ac(4); 512 threads = 8 waves.
//  wave w: wa = w>>1 (a-subtile: 16 a's), wk = w&1 (h-half: 50 h's).
//  phase B: W[b,h,i] = sum_j x*rw2 via MFMA -> LDS bf16 [i][k=h*16+b] (8 waves x 25 n-tiles)
//  phase C: 25 MFMA k-steps per wave, swish A-frag built in-register
//  epilogue: wk=1 waves dump acc to LDS, wk=0 waves add + write part (16 chunks)
// MFMA 16x16x32 bf16 frags: A[m=l&15][k=(l>>4)*4+e, +16]; B[k][n=l&15]; D col=l&15,row=(l>>4)*4+r
// ---------------------------------------------------------------------------
__global__ __launch_bounds__(512) void k2_fused(const float* __restrict__ x,
                                                const float* __restrict__ xyz,
                                                const float* __restrict__ rw1,
                                                const float* __restrict__ rw2,
                                                float* __restrict__ part) {
    extern __shared__ char smem[];
    __bf16* Wlds = (__bf16*)smem;                          // [32][WSTR]  102,912 B
    float*  rw1s = (float*)(smem + 32 * WSTR * 2);         // [304]         1,216 B
    float (*red)[2][16][17] = (float(*)[2][16][17])(smem + 32 * WSTR * 2 + 1216); // 8,704 B

    int bid = blockIdx.x;
    int ac = bid & 3;
    int bc = (bid >> 2) & 15;
    int z  = bid >> 6;
    int t  = threadIdx.x;
    int w  = t >> 6;              // 0..7
    int wa = w >> 1, wk = w & 1;
    int l  = t & 63;
    int l16 = l & 15, lg = l >> 4;

    for (int e = t; e < 300; e += 512) rw1s[e] = rw1[e];

    // ---- phase A: per-lane bas registers: a-row = l16 (of wa subtile), b = lg*4+e ----
    int a_glob = ac * 64 + wa * 16 + l16;
    float ax = xyz[(z * 256 + a_glob) * 3 + 0];
    float ay = xyz[(z * 256 + a_glob) * 3 + 1];
    float az = xyz[(z * 256 + a_glob) * 3 + 2];
    float bas[4][3];
    #pragma unroll
    for (int e = 0; e < 4; ++e) {
        int b_glob = bc * 16 + lg * 4 + e;
        float dx = xyz[(z * 256 + b_glob) * 3 + 0] - ax;
        float dy = xyz[(z * 256 + b_glob) * 3 + 1] - ay;
        float dz = xyz[(z * 256 + b_glob) * 3 + 2] - az;
        float r  = sqrtf(dx * dx + dy * dy + dz * dz + 1e-12f);
        float r5 = r - 5.f, r10 = r - 10.f;
        bas[e][0] = __expf(-GAMMA * r * r);
        bas[e][1] = __expf(-GAMMA * r5 * r5);
        bas[e][2] = __expf(-GAMMA * r10 * r10);
    }

    // ---- phase B: W chunk via MFMA (M=16 b, N=3200 hi, K=32 j), 25 n-tiles/wave ----
    bf16x8 xa;
    {
        int row = (z * 256 + bc * 16 + l16) * 32;
        float4 v0 = *(const float4*)(x + row + lg * 4);
        float4 v1 = *(const float4*)(x + row + lg * 4 + 16);
        xa[0] = (__bf16)v0.x; xa[1] = (__bf16)v0.y; xa[2] = (__bf16)v0.z; xa[3] = (__bf16)v0.w;
        xa[4] = (__bf16)v1.x; xa[5] = (__bf16)v1.y; xa[6] = (__bf16)v1.z; xa[7] = (__bf16)v1.w;
    }
    for (int q = 0; q < 25; ++q) {
        int nt = w * 25 + q;                 // 0..199
        int h  = nt >> 1;
        int icol = ((nt & 1) << 4) + l16;    // i = 0..31
        const float* rp = rw2 + h * 1024 + icol * 32 + lg * 4;
        float4 r0 = *(const float4*)rp;
        float4 r1 = *(const float4*)(rp + 16);
        bf16x8 rb;
        rb[0] = (__bf16)r0.x; rb[1] = (__bf16)r0.y; rb[2] = (__bf16)r0.z; rb[3] = (__bf16)r0.w;
        rb[4] = (__bf16)r1.x; rb[5] = (__bf16)r1.y; rb[6] = (__bf16)r1.z; rb[7] = (__bf16)r1.w;
        f32x4 d = {0.f, 0.f, 0.f, 0.f};
        d = __builtin_amdgcn_mfma_f32_16x16x32_bf16(xa, rb, d, 0, 0, 0);
        // D row r = b_local lg*4+r -> k = h*16 + lg*4 + r : 4 contiguous bf16
        bf16x4 pk;
        pk[0] = (__bf16)d[0]; pk[1] = (__bf16)d[1]; pk[2] = (__bf16)d[2]; pk[3] = (__bf16)d[3];
        *(bf16x4*)&Wlds[icol * WSTR + h * 16 + lg * 4] = pk;
    }
    __syncthreads();

    // ---- phase C: 25 MFMA k-steps over this wave's h-half (k = h*16+b) ----
    f32x4 acc0 = {0.f, 0.f, 0.f, 0.f};
    f32x4 acc1 = {0.f, 0.f, 0.f, 0.f};
    for (int ks = 0; ks < 25; ++ks) {
        int hp = wk * 25 + ks;               // h-pair index 0..49
        int h0 = 2 * hp, h1 = h0 + 1;
        float u00 = rw1s[h0],       u01 = rw1s[h1];
        float u10 = rw1s[100 + h0], u11 = rw1s[100 + h1];
        float u20 = rw1s[200 + h0], u21 = rw1s[200 + h1];
        bf16x8 af;
        #pragma unroll
        for (int e = 0; e < 4; ++e) {
            float p0 = bas[e][0] * u00 + bas[e][1] * u10 + bas[e][2] * u20;
            float p1 = bas[e][0] * u01 + bas[e][1] * u11 + bas[e][2] * u21;
            float s0 = p0 * __builtin_amdgcn_rcpf(1.f + __expf(-p0));   // swish
            float s1 = p1 * __builtin_amdgcn_rcpf(1.f + __expf(-p1));
            af[e]     = (__bf16)s0;    // k = lg*4+e      (h0, even)
            af[e + 4] = (__bf16)s1;    // k = lg*4+e+16   (h1, odd)
        }
        int kb = hp * 32 + lg * 4;
        const __bf16* w0 = &Wlds[l16 * WSTR + kb];
        const __bf16* w1 = w0 + 16 * WSTR;
        bf16x4 b0l = *(const bf16x4*)w0, b0h = *(const bf16x4*)(w0 + 16);
        bf16x4 b1l = *(const bf16x4*)w1, b1h = *(const bf16x4*)(w1 + 16);
        bf16x8 bf0 = __builtin_shufflevector(b0l, b0h, 0, 1, 2, 3, 4, 5, 6, 7);
        bf16x8 bf1 = __builtin_shufflevector(b1l, b1h, 0, 1, 2, 3, 4, 5, 6, 7);
        acc0 = __builtin_amdgcn_mfma_f32_16x16x32_bf16(af, bf0, acc0, 0, 0, 0);
        acc1 = __builtin_amdgcn_mfma_f32_16x16x32_bf16(af, bf1, acc1, 0, 0, 0);
    }

    // ---- epilogue: combine wk halves via LDS, write part (16 chunks) ----
    if (wk == 1) {
        #pragma unroll
        for (int r = 0; r < 4; ++r) {
            red[wa][0][lg * 4 + r][l16] = acc0[r];
            red[wa][1][lg * 4 + r][l16] = acc1[r];
        }
    }
    __syncthreads();
    if (wk == 0) {
        #pragma unroll
        for (int r = 0; r < 4; ++r) {
            float v0 = acc0[r] + red[wa][0][lg * 4 + r][l16];
            float v1 = acc1[r] + red[wa][1][lg * 4 + r][l16];
            int a = ac * 64 + wa * 16 + lg * 4 + r;
            size_t base = ((size_t)(z * 16 + bc) * 256 + a) * 32;
            part[base + l16]      = v0;
            part[base + 16 + l16] = v1;
        }
    }
}

// ---------------------------------------------------------------------------
// K3a: sum over 16 chunks, abs+mask+scale, pool 4 a's per block.
// grid: 256 blocks = z(4) x ag(64); 256 threads = a_loc(4) x qg(2) x i(32)
// ---------------------------------------------------------------------------
__global__ __launch_bounds__(256) void k3a_reduce(const float* __restrict__ part,
                                                  const int* __restrict__ mask,
                                                  float* __restrict__ pooled_part) {
    int blk = blockIdx.x;
    int z = blk >> 6, ag = blk & 63;
    int t = threadIdx.x;
    int i = t & 31;
    int qg = (t >> 5) & 1;
    int a_loc = t >> 6;               // 0..3
    int a = ag * 4 + a_loc;
    const float* base = part + ((size_t)z * 16 * 256 + (size_t)a) * 32 + i;
    float s = 0.f;
    for (int q = qg; q < 16; q += 2)
        s += base[(size_t)q * 8192];
    __shared__ float buf[4][2][32];
    buf[a_loc][qg][i] = s;
    __syncthreads();
    if (t < 128) {
        int al = t >> 5, ii = t & 31;
        float v = buf[al][0][ii] + buf[al][1][ii];
        float sc = (mask[z * 256 + ag * 4 + al] != 0) ? 0.0625f : 0.f;   // 1/sqrt(256)
        buf[al][0][ii] = fabsf(v) * sc;
    }
    __syncthreads();
    if (t < 32) {
        float v = buf[0][0][t] + buf[1][0][t] + buf[2][0][t] + buf[3][0][t];
        pooled_part[(z * 64 + ag) * 32 + t] = v;
    }
}

// ---------------------------------------------------------------------------
// K3b: pool over ag(64), normalize (ddof=1), fc3+leaky, fc2 -> out[4]
// ---------------------------------------------------------------------------
__global__ __launch_bounds__(128) void k3b_final(const float* __restrict__ pooled_part,
                                                 const float* __restrict__ fc3_w,
                                                 const float* __restrict__ fc3_b,
                                                 const float* __restrict__ fc2_w,
                                                 const float* __restrict__ fc2_b,
                                                 float* __restrict__ out) {
    int t = threadIdx.x;
    int z = t >> 5, i = t & 31;
    float s = 0.f;
    for (int ag = 0; ag < 64; ++ag) s += pooled_part[(z * 64 + ag) * 32 + i];
    float sm = s;
    #pragma unroll
    for (int off = 16; off; off >>= 1) sm += __shfl_xor(sm, off, 32);
    float mean = sm * (1.f / 32.f);
    float d = s - mean;
    float ss = d * d;
    #pragma unroll
    for (int off = 16; off; off >>= 1) ss += __shfl_xor(ss, off, 32);
    float stdv = sqrtf(ss * (1.f / 31.f));   // ddof=1
    float nv = d / (stdv + 1e-6f);
    __shared__ float pn[4][32];
    pn[z][i] = nv;
    __syncthreads();
    float h1 = fc3_b[i];
    #pragma unroll
    for (int j = 0; j < 32; ++j) h1 += pn[z][j] * fc3_w[j * 32 + i];
    h1 = (h1 >= 0.f) ? h1 : 0.01f * h1;
    float y = h1 * fc2_w[i];
    #pragma unroll
    for (int off = 16; off; off >>= 1) y += __shfl_xor(y, off, 32);
    if (i == 0) out[z] = y + fc2_b[0];
}

extern "C" void kernel_launch(void* const* d_in, const int* in_sizes, int n_in,
                              void* d_out, int out_size, void* d_ws, size_t ws_size,
                              hipStream_t stream) {
    const float* x    = (const float*)d_in[0];
    const float* xyz  = (const float*)d_in[1];
    const int*   mask = (const int*)d_in[2];
    const float* rw1  = (const float*)d_in[3];
    const float* rw2  = (const float*)d_in[4];
    const float* fc3w = (const float*)d_in[5];
    const float* fc3b = (const float*)d_in[6];
    const float* fc2w = (const float*)d_in[7];
    const float* fc2b = (const float*)d_in[8];
    float* out = (float*)d_out;

    // part: 4z * 16bc * 256a * 32i * 4B = 2,097,152 B
    float* part        = (float*)d_ws;
    float* pooled_part = (float*)((char*)d_ws + 2097152);   // 32 KB

    const int LDS_BYTES = 32 * WSTR * 2 + 1216 + 8704;      // 102,912 + 1,216 + 8,704 = 112,832

    hipLaunchKernelGGL(k2_fused,   dim3(256), dim3(512), LDS_BYTES, stream, x, xyz, rw1, rw2, part);
    hipLaunchKernelGGL(k3a_reduce, dim3(256), dim3(256), 0, stream, part, mask, pooled_part);
    hipLaunchKernelGGL(k3b_final,  dim3(1),   dim3(128), 0, stream, pooled_part, fc3w, fc3b, fc2w, fc2b, out);
}